// Round 22
// baseline (20461.124 us; speedup 1.0000x reference)
//
#include <hip/hip_runtime.h>
#include <math.h>

#define T_STEPS 100
#define B_SZ 256
#define DIN 768
#define H_SZ 1024
#define OUT_SZ 10
#define BH (B_SZ * H_SZ)
#define BO (B_SZ * OUT_SZ)
#define SZH (T_STEPS * BH)
#define SZO (T_STEPS * BO)
#define KC 512                    // OpenBLAS SKYLAKEX SGEMM_DEFAULT_Q hypothesis

#define OFF_CUR1 0
#define OFF_CUR2 (SZH)
#define OFF_CUR3 (2 * SZH)
#define OFF_CUR4 (3 * SZH)
#define OFF_MEM1 (3 * SZH + SZO)
#define OFF_MEM2 (4 * SZH + SZO)
#define OFF_MEM3 (5 * SZH + SZO)
#define OFF_MEM4 (6 * SZH + SZO)

#define WS_M1   0
#define WS_M2   (WS_M1 + BH)
#define WS_M3   (WS_M2 + BH)
#define WS_M4   (WS_M3 + BH)
#define WS_SPK1 (WS_M4 + BO)
#define WS_SPK2 (WS_SPK1 + BH)
#define WS_SPK3 (WS_SPK2 + BH)
#define WS_W1T  (WS_SPK3 + BH)
#define WS_W2T  (WS_W1T + DIN * H_SZ)
#define WS_W3T  (WS_W2T + H_SZ * H_SZ)

// strict numpy f32 LIF: r=(m>1); mn=((0.95f*m)+c)-r; sp=(mn>1)
__device__ __forceinline__ void lif_np(float c, float& m, float& sp) {
    float r  = (m > 1.0f) ? 1.0f : 0.0f;
    float t1 = __fmul_rn(0.95f, m);
    float t2 = __fadd_rn(t1, c);
    m = __fsub_rn(t2, r);
    sp = (m > 1.0f) ? 1.0f : 0.0f;
}

// ---------------------------------------------------------------------------
// W[N][K] -> Wt[K][N], f32 exact copy
// ---------------------------------------------------------------------------
__global__ __launch_bounds__(256) void wtrans(const float* __restrict__ W,
                                              float* __restrict__ Wt, int N, int K) {
    int id = blockIdx.x * 256 + threadIdx.x;
    if (id < N * K) {
        int k = id / N, n = id - k * N;
        Wt[id] = W[(size_t)n * K + k];
    }
}

// ---------------------------------------------------------------------------
// cur1 for ALL (t,b): rows r = b*T + t (x-linear). OpenBLAS-SKYLAKEX replica:
// K=768 -> KC panels [0,512),[512,768); each panel an ascending-k
// single-accumulator fmaf chain; panels chained through C (S0 then +S1, one
// f32 rounding); then one separate bias add.
// grid (6400, 4), block 256: 4 rows/block, 256 h per y-slice.
// ---------------------------------------------------------------------------
__global__ __launch_bounds__(256) void layer1_all(
    const float* __restrict__ x, const float* __restrict__ W1t,
    const float* __restrict__ b1, float* __restrict__ cur1)
{
    __shared__ float xs[4][DIN];
    const int tid = threadIdx.x;
    const int h = blockIdx.y * 256 + tid;
    const int r0 = blockIdx.x * 4;
    for (int i = tid; i < 4 * DIN; i += 256) {
        int row = i / DIN, k = i - row * DIN;
        xs[row][k] = x[(size_t)(r0 + row) * DIN + k];
    }
    __syncthreads();
    float s0[4] = {0.f, 0.f, 0.f, 0.f};
    float s1[4] = {0.f, 0.f, 0.f, 0.f};
#pragma unroll 4
    for (int k = 0; k < KC; ++k) {
        float w = W1t[(size_t)k * H_SZ + h];
#pragma unroll
        for (int j = 0; j < 4; ++j) s0[j] = fmaf(xs[j][k], w, s0[j]);
    }
#pragma unroll 4
    for (int k = KC; k < DIN; ++k) {
        float w = W1t[(size_t)k * H_SZ + h];
#pragma unroll
        for (int j = 0; j < 4; ++j) s1[j] = fmaf(xs[j][k], w, s1[j]);
    }
    const float bias = b1[h];
#pragma unroll
    for (int j = 0; j < 4; ++j) {
        int r = r0 + j;
        int b = r / T_STEPS, t = r - b * T_STEPS;
        float c = __fadd_rn(__fadd_rn(s0[j], s1[j]), bias);
        cur1[(size_t)t * BH + (size_t)b * H_SZ + h] = c;
    }
}

// ---------------------------------------------------------------------------
// LIF1 for one timestep, elementwise [B,H], strict f32 semantics.
// ---------------------------------------------------------------------------
__global__ __launch_bounds__(256) void lif1_step(
    const float* __restrict__ cur1_t, float* __restrict__ m1,
    float* __restrict__ mem1_t, float* __restrict__ spk1)
{
    int i = blockIdx.x * 256 + threadIdx.x;
    float c = cur1_t[i];
    float m = m1[i], sp;
    lif_np(c, m, sp);
    m1[i] = m;
    mem1_t[i] = m;
    spk1[i] = sp;
}

// ---------------------------------------------------------------------------
// Hidden layer (2/3): K=1024 -> panels 512+512, single-acc ascending chains,
// chained combine, separate bias, strict f32 LIF.
// grid (64, 4): 4 b/block, 256 h per y-slice.
// ---------------------------------------------------------------------------
__global__ __launch_bounds__(256) void layerH_k(
    const float* __restrict__ A, const float* __restrict__ Wt,
    const float* __restrict__ bias,
    float* __restrict__ m, float* __restrict__ cur_out,
    float* __restrict__ mem_out, float* __restrict__ spk_out)
{
    __shared__ float as[4][H_SZ];
    const int tid = threadIdx.x;
    const int h  = blockIdx.y * 256 + tid;
    const int b0 = blockIdx.x * 4;
    for (int i = tid; i < 4 * H_SZ; i += 256) {
        int bb = i >> 10, k = i & 1023;
        as[bb][k] = A[(size_t)(b0 + bb) * H_SZ + k];
    }
    __syncthreads();
    float s0[4] = {0.f, 0.f, 0.f, 0.f};
    float s1[4] = {0.f, 0.f, 0.f, 0.f};
#pragma unroll 4
    for (int k = 0; k < KC; ++k) {
        float w = Wt[(size_t)k * H_SZ + h];
#pragma unroll
        for (int j = 0; j < 4; ++j) s0[j] = fmaf(as[j][k], w, s0[j]);
    }
#pragma unroll 4
    for (int k = KC; k < H_SZ; ++k) {
        float w = Wt[(size_t)k * H_SZ + h];
#pragma unroll
        for (int j = 0; j < 4; ++j) s1[j] = fmaf(as[j][k], w, s1[j]);
    }
    const float bd = bias[h];
#pragma unroll
    for (int j = 0; j < 4; ++j) {
        int idx = (b0 + j) * H_SZ + h;
        float c = __fadd_rn(__fadd_rn(s0[j], s1[j]), bd);
        float mm = m[idx], sp;
        lif_np(c, mm, sp);
        cur_out[idx] = c;
        mem_out[idx] = mm;
        m[idx] = mm;
        spk_out[idx] = sp;
    }
}

// ---------------------------------------------------------------------------
// Layer 4: K=1024 panels 512+512, N=10. One block per b, tid<10 active.
// W4 in native [N][K] layout.
// ---------------------------------------------------------------------------
__global__ __launch_bounds__(64) void layer4_k(
    const float* __restrict__ spk3, const float* __restrict__ W4,
    const float* __restrict__ b4,
    float* __restrict__ m4, float* __restrict__ cur_out, float* __restrict__ mem_out)
{
    __shared__ float s3v[H_SZ];
    const int tid = threadIdx.x;
    const int b = blockIdx.x;
    for (int i = tid; i < H_SZ; i += 64) s3v[i] = spk3[(size_t)b * H_SZ + i];
    __syncthreads();
    if (tid < OUT_SZ) {
        const int n = tid;
        float s0 = 0.f, s1 = 0.f;
        for (int k = 0; k < KC; ++k)
            s0 = fmaf(s3v[k], W4[(size_t)n * H_SZ + k], s0);
        for (int k = KC; k < H_SZ; ++k)
            s1 = fmaf(s3v[k], W4[(size_t)n * H_SZ + k], s1);
        float c = __fadd_rn(__fadd_rn(s0, s1), b4[n]);
        int o = b * OUT_SZ + n;
        float mm = m4[o];
        float r  = (mm > 1.0f) ? 1.0f : 0.0f;
        float t1 = __fmul_rn(0.95f, mm);
        float t2 = __fadd_rn(t1, c);
        mm = __fsub_rn(t2, r);
        m4[o] = mm;
        cur_out[o] = c;
        mem_out[o] = mm;
    }
}

extern "C" void kernel_launch(void* const* d_in, const int* in_sizes, int n_in,
                              void* d_out, int out_size, void* d_ws, size_t ws_size,
                              hipStream_t stream)
{
    const float* x  = (const float*)d_in[0];
    const float* W1 = (const float*)d_in[1];
    const float* b1 = (const float*)d_in[2];
    const float* W2 = (const float*)d_in[3];
    const float* b2 = (const float*)d_in[4];
    const float* W3 = (const float*)d_in[5];
    const float* b3 = (const float*)d_in[6];
    const float* W4 = (const float*)d_in[7];
    const float* b4 = (const float*)d_in[8];
    float* out = (float*)d_out;
    float* ws  = (float*)d_ws;

    float* m1   = ws + WS_M1;
    float* m2   = ws + WS_M2;
    float* m3   = ws + WS_M3;
    float* m4   = ws + WS_M4;
    float* spk1 = ws + WS_SPK1;
    float* spk2 = ws + WS_SPK2;
    float* spk3 = ws + WS_SPK3;
    float* W1t  = ws + WS_W1T;
    float* W2t  = ws + WS_W2T;
    float* W3t  = ws + WS_W3T;

    hipMemsetAsync((void*)m1, 0, (size_t)(3 * BH + BO) * sizeof(float), stream);

    wtrans<<<(H_SZ * DIN + 255) / 256, 256, 0, stream>>>(W1, W1t, H_SZ, DIN);
    wtrans<<<(H_SZ * H_SZ + 255) / 256, 256, 0, stream>>>(W2, W2t, H_SZ, H_SZ);
    wtrans<<<(H_SZ * H_SZ + 255) / 256, 256, 0, stream>>>(W3, W3t, H_SZ, H_SZ);

    // cur1 for all timesteps: KC=512 panel chains + separate bias
    layer1_all<<<dim3(B_SZ * T_STEPS / 4, 4), 256, 0, stream>>>(x, W1t, b1, out + OFF_CUR1);

    for (int t = 0; t < T_STEPS; ++t) {
        size_t oh = (size_t)t * BH;
        size_t oo = (size_t)t * BO;
        lif1_step<<<BH / 256, 256, 0, stream>>>(out + OFF_CUR1 + oh, m1,
                                                out + OFF_MEM1 + oh, spk1);
        layerH_k<<<dim3(B_SZ / 4, 4), 256, 0, stream>>>(spk1, W2t, b2, m2,
                                                out + OFF_CUR2 + oh, out + OFF_MEM2 + oh, spk2);
        layerH_k<<<dim3(B_SZ / 4, 4), 256, 0, stream>>>(spk2, W3t, b3, m3,
                                                out + OFF_CUR3 + oh, out + OFF_MEM3 + oh, spk3);
        layer4_k<<<B_SZ, 64, 0, stream>>>(spk3, W4, b4, m4,
                                                out + OFF_CUR4 + oo, out + OFF_MEM4 + oo);
    }
}